// Round 1
// baseline (1522.321 us; speedup 1.0000x reference)
//
#include <hip/hip_runtime.h>
#include <hip/hip_bf16.h>
#include <cstdint>
#include <cstddef>

#define B 64
#define T 512
#define EMBED 128
#define H 128
#define G4 512          // 4*H
#define HOUT 256        // 2*H (bilstm concat)
#define NUM_CLASSES 10
#define BT (B * T)      // 32768

// ---------------------------------------------------------------------------
// 1) gather: A0[row, :] = emb[x[row], :]
// ---------------------------------------------------------------------------
__global__ __launch_bounds__(EMBED) void gather_kernel(
    const int* __restrict__ x, const float* __restrict__ emb,
    float* __restrict__ A0)
{
    int row = blockIdx.x;
    int tok = x[row];
    A0[(size_t)row * EMBED + threadIdx.x] = emb[(size_t)tok * EMBED + threadIdx.x];
}

// ---------------------------------------------------------------------------
// 2) GEMM: C(M,G4) = A(M,K) @ W(K,G4) + bias(G4)
//    BM=128, BN=64, BK=16, 256 threads, 8x4 micro-tile
// ---------------------------------------------------------------------------
#define BM 128
#define BN 64
#define BK 16

__global__ __launch_bounds__(256) void gemm_bias_kernel(
    const float* __restrict__ A, const float* __restrict__ W,
    const float* __restrict__ bias, float* __restrict__ C, int K)
{
    __shared__ __align__(16) float As[BK][BM + 4];  // transposed: As[k][m]
    __shared__ __align__(16) float Ws[BK][BN + 4];  // Ws[k][n]

    int tid = threadIdx.x;
    int tx = tid & 15;    // N direction, 16 x 4 = 64
    int ty = tid >> 4;    // M direction, 16 x 8 = 128
    int m0 = blockIdx.y * BM;
    int n0 = blockIdx.x * BN;

    float acc[8][4];
#pragma unroll
    for (int i = 0; i < 8; i++)
#pragma unroll
        for (int j = 0; j < 4; j++) acc[i][j] = 0.f;

    for (int k0 = 0; k0 < K; k0 += BK) {
        // A tile: 128 rows x 16 k = 512 float4, 2 per thread (store transposed)
#pragma unroll
        for (int i = 0; i < 2; i++) {
            int idx = tid + i * 256;          // 0..511
            int r   = idx >> 2;               // 0..127
            int cq  = idx & 3;                // float4 slot in k
            float4 a = *(const float4*)&A[(size_t)(m0 + r) * K + k0 + cq * 4];
            As[cq * 4 + 0][r] = a.x;
            As[cq * 4 + 1][r] = a.y;
            As[cq * 4 + 2][r] = a.z;
            As[cq * 4 + 3][r] = a.w;
        }
        // W tile: 16 k x 64 n = 256 float4, 1 per thread
        {
            int rw = tid >> 4;                // 0..15
            int cq = tid & 15;
            float4 wv = *(const float4*)&W[(size_t)(k0 + rw) * G4 + n0 + cq * 4];
            *(float4*)&Ws[rw][cq * 4] = wv;
        }
        __syncthreads();

#pragma unroll
        for (int k = 0; k < BK; k++) {
            float4 a0 = *(const float4*)&As[k][ty * 8];
            float4 a1 = *(const float4*)&As[k][ty * 8 + 4];
            float4 w0 = *(const float4*)&Ws[k][tx * 4];
            float av[8] = {a0.x, a0.y, a0.z, a0.w, a1.x, a1.y, a1.z, a1.w};
            float wv[4] = {w0.x, w0.y, w0.z, w0.w};
#pragma unroll
            for (int i = 0; i < 8; i++)
#pragma unroll
                for (int j = 0; j < 4; j++)
                    acc[i][j] = fmaf(av[i], wv[j], acc[i][j]);
        }
        __syncthreads();
    }

    float4 bv = *(const float4*)&bias[n0 + tx * 4];
#pragma unroll
    for (int i = 0; i < 8; i++) {
        int m = m0 + ty * 8 + i;
        float4 o;
        o.x = acc[i][0] + bv.x;
        o.y = acc[i][1] + bv.y;
        o.z = acc[i][2] + bv.z;
        o.w = acc[i][3] + bv.w;
        *(float4*)&C[(size_t)m * G4 + n0 + tx * 4] = o;
    }
}

// ---------------------------------------------------------------------------
// 3) LSTM scan: one WG per (batch, direction). Thread j owns Wh column j in
//    VGPRs. h broadcast via LDS. Writes hout channels [dir*H, dir*H+H).
// ---------------------------------------------------------------------------
__device__ __forceinline__ float sigf(float x) { return 1.f / (1.f + expf(-x)); }

__global__ __launch_bounds__(512, 1) void lstm_scan_kernel(
    const float* __restrict__ xp0, const float* __restrict__ xp1,
    const float* __restrict__ Wh0, const float* __restrict__ Wh1,
    const int* __restrict__ x, float* __restrict__ hout)
{
    int b   = blockIdx.x;
    int dir = blockIdx.y;  // 0 = forward, 1 = reverse
    const float* __restrict__ xp = dir ? xp1 : xp0;
    const float* __restrict__ Wh = dir ? Wh1 : Wh0;
    int j = threadIdx.x;

    // recurrent weight column j -> registers
    float w[H];
#pragma unroll
    for (int k = 0; k < H; k++) w[k] = Wh[(size_t)k * G4 + j];

    __shared__ __align__(16) float h_sh[H];
    __shared__ __align__(16) float z_sh[G4];
    __shared__ unsigned char mask_sh[T];

    if (j < H) h_sh[j] = 0.f;
    mask_sh[j] = (x[(size_t)b * T + j] != 0) ? 1 : 0;  // blockDim == T == 512
    float cj = 0.f, hj = 0.f;
    __syncthreads();

    float xp_next = xp[((size_t)b * T + (dir ? T - 1 : 0)) * G4 + j];

    for (int s = 0; s < T; s++) {
        int t = dir ? (T - 1 - s) : s;
        float zacc = xp_next;
        if (s + 1 < T) {  // prefetch next step's xp (uniform branch)
            int tn = dir ? (T - 2 - s) : (s + 1);
            xp_next = xp[((size_t)b * T + tn) * G4 + j];
        }
#pragma unroll
        for (int k = 0; k < H; k += 4) {
            float4 h4 = *(const float4*)&h_sh[k];  // broadcast read
            zacc = fmaf(h4.x, w[k + 0], zacc);
            zacc = fmaf(h4.y, w[k + 1], zacc);
            zacc = fmaf(h4.z, w[k + 2], zacc);
            zacc = fmaf(h4.w, w[k + 3], zacc);
        }
        z_sh[j] = zacc;
        __syncthreads();
        if (j < H) {
            float zi = z_sh[j], zf = z_sh[j + H], zg = z_sh[j + 2 * H], zo = z_sh[j + 3 * H];
            float ig = sigf(zi);
            float fg = sigf(zf);
            float gg = tanhf(zg);
            float og = sigf(zo);
            float cn = fg * cj + ig * gg;
            float hn = og * tanhf(cn);
            if (mask_sh[t]) { cj = cn; hj = hn; }
            h_sh[j] = hj;
            hout[((size_t)b * T + t) * HOUT + dir * H + j] = hj;
        }
        __syncthreads();
    }
}

// ---------------------------------------------------------------------------
// 4) pooling: per (b,t) max & mean over 256 channels -> feat (B, 2T)
// ---------------------------------------------------------------------------
__global__ __launch_bounds__(256) void pool_kernel(
    const float* __restrict__ Hin, float* __restrict__ feat)
{
    int wave = threadIdx.x >> 6;
    int lane = threadIdx.x & 63;
    int bt = blockIdx.x * 4 + wave;
    float4 v = *(const float4*)&Hin[(size_t)bt * HOUT + lane * 4];
    float mx = fmaxf(fmaxf(v.x, v.y), fmaxf(v.z, v.w));
    float sm = (v.x + v.y) + (v.z + v.w);
#pragma unroll
    for (int off = 32; off > 0; off >>= 1) {
        mx = fmaxf(mx, __shfl_down(mx, off));
        sm += __shfl_down(sm, off);
    }
    if (lane == 0) {
        int b = bt >> 9;        // /T
        int t = bt & (T - 1);
        feat[(size_t)b * (2 * T) + t]     = mx;
        feat[(size_t)b * (2 * T) + T + t] = sm * (1.f / 256.f);
    }
}

// ---------------------------------------------------------------------------
// 5) FC: out(B,10) = relu(feat(B,1024) @ fcW(1024,10) + fcb)
// ---------------------------------------------------------------------------
__global__ __launch_bounds__(128) void fc_kernel(
    const float* __restrict__ feat, const float* __restrict__ fcW,
    const float* __restrict__ fcb, float* __restrict__ out)
{
    __shared__ float red[2][NUM_CLASSES];
    int b = blockIdx.x, tid = threadIdx.x;
    float acc[NUM_CLASSES];
#pragma unroll
    for (int c = 0; c < NUM_CLASSES; c++) acc[c] = 0.f;
#pragma unroll
    for (int it = 0; it < 8; it++) {
        int k = tid + it * 128;
        float fv = feat[(size_t)b * 1024 + k];
#pragma unroll
        for (int c = 0; c < NUM_CLASSES; c++)
            acc[c] = fmaf(fv, fcW[(size_t)k * NUM_CLASSES + c], acc[c]);
    }
#pragma unroll
    for (int c = 0; c < NUM_CLASSES; c++) {
        float v = acc[c];
        for (int off = 32; off > 0; off >>= 1) v += __shfl_down(v, off);
        if ((tid & 63) == 0) red[tid >> 6][c] = v;
    }
    __syncthreads();
    if (tid < NUM_CLASSES) {
        float v = red[0][tid] + red[1][tid] + fcb[tid];
        out[(size_t)b * NUM_CLASSES + tid] = fmaxf(v, 0.f);
    }
}

// ---------------------------------------------------------------------------
// launch
// ---------------------------------------------------------------------------
extern "C" void kernel_launch(void* const* d_in, const int* in_sizes, int n_in,
                              void* d_out, int out_size, void* d_ws, size_t ws_size,
                              hipStream_t stream)
{
    const int*   x     = (const int*)d_in[0];
    const float* emb   = (const float*)d_in[1];
    const float* Wx_f0 = (const float*)d_in[2];
    const float* Wh_f0 = (const float*)d_in[3];
    const float* b_f0  = (const float*)d_in[4];
    const float* Wx_b0 = (const float*)d_in[5];
    const float* Wh_b0 = (const float*)d_in[6];
    const float* b_b0  = (const float*)d_in[7];
    const float* Wx_f1 = (const float*)d_in[8];
    const float* Wh_f1 = (const float*)d_in[9];
    const float* b_f1  = (const float*)d_in[10];
    const float* Wx_b1 = (const float*)d_in[11];
    const float* Wh_b1 = (const float*)d_in[12];
    const float* b_b1  = (const float*)d_in[13];
    const float* fcW   = (const float*)d_in[14];
    const float* fcb   = (const float*)d_in[15];
    float* out = (float*)d_out;

    char* ws = (char*)d_ws;
    const size_t MB = 1024 * 1024;
    // A0 [0,16MB) is dead after the layer-0 GEMMs; H1 overlays [0,32MB).
    float* A0   = (float*)(ws);                  // 16 MB  (BT x 128)
    float* H1   = (float*)(ws);                  // 32 MB  (BT x 256) - overlaps A0
    float* H0   = (float*)(ws + 32 * MB);        // 32 MB  (BT x 256)
    float* xpF  = (float*)(ws + 64 * MB);        // 64 MB  (BT x 512)
    float* xpB  = (float*)(ws + 128 * MB);       // 64 MB  (BT x 512)
    float* feat = (float*)(ws + 192 * MB);       // 256 KB (B x 1024)

    dim3 ggrid(G4 / BN, BT / BM);  // (8, 256)

    // layer 0
    gather_kernel<<<BT, EMBED, 0, stream>>>(x, emb, A0);
    gemm_bias_kernel<<<ggrid, 256, 0, stream>>>(A0, Wx_f0, b_f0, xpF, EMBED);
    gemm_bias_kernel<<<ggrid, 256, 0, stream>>>(A0, Wx_b0, b_b0, xpB, EMBED);
    lstm_scan_kernel<<<dim3(B, 2), 512, 0, stream>>>(xpF, xpB, Wh_f0, Wh_b0, x, H0);

    // layer 1 (input = H0, K = 256)
    gemm_bias_kernel<<<ggrid, 256, 0, stream>>>(H0, Wx_f1, b_f1, xpF, 2 * H);
    gemm_bias_kernel<<<ggrid, 256, 0, stream>>>(H0, Wx_b1, b_b1, xpB, 2 * H);
    lstm_scan_kernel<<<dim3(B, 2), 512, 0, stream>>>(xpF, xpB, Wh_f1, Wh_b1, x, H1);

    // pooling + FC
    pool_kernel<<<BT / 4, 256, 0, stream>>>(H1, feat);
    fc_kernel<<<B, 128, 0, stream>>>(feat, fcW, fcb, out);
}